// Round 1
// baseline (316.359 us; speedup 1.0000x reference)
//
#include <hip/hip_runtime.h>

// MHSA: B=4, N=2048, C=1024, H=16, HD=64, SCALE=0.125
// Pipeline: cast(f32->bf16) -> GEMM1 (qkv proj, split epilogue) -> flash attn -> GEMM2 (+bias)

typedef float f32x4 __attribute__((ext_vector_type(4)));
typedef __bf16 bf16x8 __attribute__((ext_vector_type(8)));
typedef __bf16 bf16x4 __attribute__((ext_vector_type(4)));
typedef __bf16 bf16x2 __attribute__((ext_vector_type(2)));

__device__ __forceinline__ void async16(const void* g, void* l) {
  __builtin_amdgcn_global_load_lds((const __attribute__((address_space(1))) unsigned int*)g,
                                   (__attribute__((address_space(3))) unsigned int*)l, 16, 0, 0);
}

// ---------------- cast kernel: x (8.4M), w_qkv (3.1M), w_proj (1M) f32 -> bf16 ----------------
__global__ __launch_bounds__(256) void cast_to_bf16(const float* __restrict__ x,
                                                    const float* __restrict__ wq,
                                                    const float* __restrict__ wp,
                                                    __bf16* __restrict__ xo,
                                                    __bf16* __restrict__ wqo,
                                                    __bf16* __restrict__ wpo) {
  long i = (long)blockIdx.x * 256 + threadIdx.x;   // vec4 index, total 3,145,728
  const float* s; __bf16* d; long j;
  if (i < 2097152L)      { s = x;  d = xo;  j = i; }
  else if (i < 2883584L) { s = wq; d = wqo; j = i - 2097152L; }
  else                   { s = wp; d = wpo; j = i - 2883584L; }
  float4 v = ((const float4*)s)[j];
  bf16x4 o = { (__bf16)v.x, (__bf16)v.y, (__bf16)v.z, (__bf16)v.w };
  ((bf16x4*)d)[j] = o;
}

// ---------------- GEMM (B^T): C[m][n] = sum_k A[m][k] * W[n][k].  M blocks x, N blocks y. ----
// 128x128 tile, BK=32, 4 waves (2x2), each wave 4x4 frags of 16x16x32 bf16 MFMA (m97 structure).
// EPI=0: split-qkv bf16 epilogue (scale Q by 0.125).  EPI=1: f32 + bias epilogue to d_out.
template <int EPI>
__global__ __launch_bounds__(256) void gemm_bt(const __bf16* __restrict__ A,
                                               const __bf16* __restrict__ Bw,
                                               __bf16* __restrict__ Oq,
                                               float* __restrict__ Of,
                                               const float* __restrict__ bias) {
  const int tid = threadIdx.x;
  const int lane = tid & 63, w = tid >> 6;
  const int arow = lane & 15, agrp = lane >> 4;
  const int wm = w >> 1, wn = w & 1;
  const int bm = blockIdx.x, bn = blockIdx.y;
  __shared__ __bf16 As[128 * 32];
  __shared__ __bf16 Bs[128 * 32];
  f32x4 acc[4][4] = {};

  const int c0 = tid, c1 = tid + 256;  // 16B-chunk ids; row = c>>2, col8 = c&3 (row = 64B)
  const __bf16* Ag0 = A + ((size_t)(bm * 128 + (c0 >> 2)) << 10) + (c0 & 3) * 8;
  const __bf16* Ag1 = A + ((size_t)(bm * 128 + (c1 >> 2)) << 10) + (c1 & 3) * 8;
  const __bf16* Bg0 = Bw + ((size_t)(bn * 128 + (c0 >> 2)) << 10) + (c0 & 3) * 8;
  const __bf16* Bg1 = Bw + ((size_t)(bn * 128 + (c1 >> 2)) << 10) + (c1 & 3) * 8;

  for (int kt = 0; kt < 1024; kt += 32) {
    async16(Ag0 + kt, &As[c0 * 8]);
    async16(Ag1 + kt, &As[c1 * 8]);
    async16(Bg0 + kt, &Bs[c0 * 8]);
    async16(Bg1 + kt, &Bs[c1 * 8]);
    __syncthreads();  // drains vmcnt (compiler inserts)
    bf16x8 af[4], bfr[4];
#pragma unroll
    for (int mi = 0; mi < 4; ++mi)
      af[mi] = *(const bf16x8*)&As[(wm * 64 + mi * 16 + arow) * 32 + agrp * 8];
#pragma unroll
    for (int ni = 0; ni < 4; ++ni)
      bfr[ni] = *(const bf16x8*)&Bs[(wn * 64 + ni * 16 + arow) * 32 + agrp * 8];
#pragma unroll
    for (int mi = 0; mi < 4; ++mi)
#pragma unroll
      for (int ni = 0; ni < 4; ++ni)
        acc[mi][ni] = __builtin_amdgcn_mfma_f32_16x16x32_bf16(af[mi], bfr[ni], acc[mi][ni], 0, 0, 0);
    __syncthreads();
  }

  // D layout (m89-verified): col = lane&15, row = (lane>>4)*4 + reg
  const int rowb = bm * 128 + wm * 64 + agrp * 4;
  const int colb = bn * 128 + wn * 64 + arow;
  if (EPI == 0) {
#pragma unroll
    for (int mi = 0; mi < 4; ++mi) {
      const int row = rowb + mi * 16;
      const int bidx = row >> 11;  // batch (constant within a 128-row block)
#pragma unroll
      for (int ni = 0; ni < 4; ++ni) {
        f32x4 v = acc[mi][ni];
        const int col = colb + ni * 16;
        const int which = col >> 10;          // 0=q 1=k 2=v
        const int h = (col >> 6) & 15;
        const int hd = col & 63;
        const float s = (which == 0) ? 0.125f : 1.0f;
        __bf16* dst = Oq + ((size_t)which * 64 + bidx * 16 + h) * (size_t)(2048 * 64) + hd;
#pragma unroll
        for (int i = 0; i < 4; ++i)
          dst[(size_t)((row + i) & 2047) * 64] = (__bf16)(v[i] * s);
      }
    }
  } else {
#pragma unroll
    for (int mi = 0; mi < 4; ++mi) {
      const int row = rowb + mi * 16;
#pragma unroll
      for (int ni = 0; ni < 4; ++ni) {
        const int col = colb + ni * 16;
        const float bv = bias[col];
        f32x4 v = acc[mi][ni];
#pragma unroll
        for (int i = 0; i < 4; ++i)
          Of[(size_t)(row + i) * 1024 + col] = v[i] + bv;
      }
    }
  }
}

// ---------------- flash attention ----------------
// QKV: [3][64 bh][2048][64] bf16 (Q pre-scaled by 0.125). Out: [4][2048][1024] bf16.
// Block: 256 thr / 4 waves; wave owns 16 q-rows; KV tile = 64 keys.
// K LDS: row-major [64][64] XOR-swizzled (byte ^= (row&7)<<4).  V LDS: transposed [d][key], swizzled.
__global__ __launch_bounds__(256) void mhsa_attn(const __bf16* __restrict__ QKV,
                                                 __bf16* __restrict__ Out) {
  const int tid = threadIdx.x;
  const int lane = tid & 63, w = tid >> 6;
  const int bh = blockIdx.x;  // 0..63 (b*16+h); same-bh blocks share an XCD (id%8 = bh%8)
  const int qt = blockIdx.y;  // 0..31
  const int arow = lane & 15, agrp = lane >> 4;

  const size_t bhoff = (size_t)bh * (2048 * 64);
  const __bf16* Qp = QKV + bhoff;
  const __bf16* Kp = QKV + (size_t)64 * 2048 * 64 + bhoff;
  const __bf16* Vp = QKV + (size_t)128 * 2048 * 64 + bhoff;

  __shared__ __bf16 Ks[64 * 64];
  __shared__ __bf16 VT[64 * 64];
  __shared__ __bf16 Ps[4][16 * 64];

  const int r0 = qt * 64 + w * 16;
  bf16x8 qf[2];
#pragma unroll
  for (int kc = 0; kc < 2; ++kc)
    qf[kc] = *(const bf16x8*)&Qp[(size_t)(r0 + arow) * 64 + kc * 32 + agrp * 8];

  float m_run[4], l_run[4];
  f32x4 Oacc[4];
#pragma unroll
  for (int i = 0; i < 4; ++i) { m_run[i] = -1e30f; l_run[i] = 0.f; Oacc[i] = f32x4{0.f, 0.f, 0.f, 0.f}; }

  // staging indices: K tile chunks (row=c>>3, col8=c&7); V: d-chunk=tid>>5, key pair=(tid&31)*2
  const int kr0 = tid >> 3, kc8 = tid & 7;
  const int kr1 = (tid + 256) >> 3;
  const int c8v = tid >> 5, k0v = (tid & 31) * 2;

  char* KsB = (char*)Ks;
  char* VTB = (char*)VT;
  char* PsB = (char*)&Ps[w][0];

  for (int kt = 0; kt < 2048; kt += 64) {
    // ---- stage K (swizzled row-major) ----
    bf16x8 kv0 = *(const bf16x8*)&Kp[(size_t)(kt + kr0) * 64 + kc8 * 8];
    bf16x8 kv1 = *(const bf16x8*)&Kp[(size_t)(kt + kr1) * 64 + kc8 * 8];
    *(bf16x8*)(KsB + ((kr0 * 128 + kc8 * 16) ^ ((kr0 & 7) << 4))) = kv0;
    *(bf16x8*)(KsB + ((kr1 * 128 + kc8 * 16) ^ ((kr1 & 7) << 4))) = kv1;
    // ---- stage V transposed (packed u32 writes, conflict-free) ----
    bf16x8 v0 = *(const bf16x8*)&Vp[(size_t)(kt + k0v) * 64 + c8v * 8];
    bf16x8 v1 = *(const bf16x8*)&Vp[(size_t)(kt + k0v + 1) * 64 + c8v * 8];
#pragma unroll
    for (int j = 0; j < 8; ++j) {
      const int d = c8v * 8 + j;
      bf16x2 pr = { v0[j], v1[j] };
      *(bf16x2*)(VTB + ((d * 128 + k0v * 2) ^ ((d & 7) << 4))) = pr;
    }
    __syncthreads();

    // ---- S = Q K^T (per wave: 16 q-rows x 64 keys) ----
    f32x4 sacc[4] = {};
#pragma unroll
    for (int kb = 0; kb < 4; ++kb) {
      const int key = kb * 16 + arow;
#pragma unroll
      for (int kc = 0; kc < 2; ++kc) {
        const int d0 = kc * 32 + agrp * 8;
        bf16x8 kf = *(const bf16x8*)(KsB + ((key * 128 + d0 * 2) ^ ((key & 7) << 4)));
        sacc[kb] = __builtin_amdgcn_mfma_f32_16x16x32_bf16(qf[kc], kf, sacc[kb], 0, 0, 0);
      }
    }

    // ---- online softmax (wave-parallel: 16-lane group reduce per q-row) ----
    float p[4][4];
#pragma unroll
    for (int i = 0; i < 4; ++i) {
      float m0 = fmaxf(fmaxf(sacc[0][i], sacc[1][i]), fmaxf(sacc[2][i], sacc[3][i]));
#pragma unroll
      for (int dd = 1; dd < 16; dd <<= 1) m0 = fmaxf(m0, __shfl_xor(m0, dd, 64));
      const float mn = fmaxf(m_run[i], m0);
      const float fs = __expf(m_run[i] - mn);
      m_run[i] = mn;
      float s0 = 0.f;
#pragma unroll
      for (int kb = 0; kb < 4; ++kb) { p[kb][i] = __expf(sacc[kb][i] - mn); s0 += p[kb][i]; }
#pragma unroll
      for (int dd = 1; dd < 16; dd <<= 1) s0 += __shfl_xor(s0, dd, 64);
      l_run[i] = l_run[i] * fs + s0;
#pragma unroll
      for (int db = 0; db < 4; ++db) Oacc[db][i] *= fs;
    }

    // ---- P -> per-wave LDS (transpose to MFMA A-layout) ----
#pragma unroll
    for (int kb = 0; kb < 4; ++kb)
#pragma unroll
      for (int i = 0; i < 4; ++i) {
        const int row = agrp * 4 + i, key = kb * 16 + arow;
        *(__bf16*)(PsB + ((row * 128 + key * 2) ^ ((row & 7) << 4))) = (__bf16)p[kb][i];
      }
    bf16x8 pa[2];
#pragma unroll
    for (int kk = 0; kk < 2; ++kk)
      pa[kk] = *(const bf16x8*)(PsB + ((arow * 128 + (kk * 32 + agrp * 8) * 2) ^ ((arow & 7) << 4)));

    // ---- O += P V ----
#pragma unroll
    for (int db = 0; db < 4; ++db) {
      const int d = db * 16 + arow;
#pragma unroll
      for (int kk = 0; kk < 2; ++kk) {
        const int key0 = kk * 32 + agrp * 8;
        bf16x8 vf = *(const bf16x8*)(VTB + ((d * 128 + key0 * 2) ^ ((d & 7) << 4)));
        Oacc[db] = __builtin_amdgcn_mfma_f32_16x16x32_bf16(pa[kk], vf, Oacc[db], 0, 0, 0);
      }
    }
    __syncthreads();
  }

  // ---- epilogue: out[b][q][h*64+d] bf16 ----
  const int b = bh >> 4, h = bh & 15;
#pragma unroll
  for (int db = 0; db < 4; ++db)
#pragma unroll
    for (int i = 0; i < 4; ++i) {
      const int q = r0 + agrp * 4 + i;
      const int col = h * 64 + db * 16 + arow;
      Out[((size_t)b * 2048 + q) * 1024 + col] = (__bf16)(Oacc[db][i] / l_run[i]);
    }
}

// ---------------- launcher ----------------
extern "C" void kernel_launch(void* const* d_in, const int* in_sizes, int n_in,
                              void* d_out, int out_size, void* d_ws, size_t ws_size,
                              hipStream_t stream) {
  const float* x  = (const float*)d_in[0];
  const float* wq = (const float*)d_in[1];
  const float* wp = (const float*)d_in[2];
  const float* bp = (const float*)d_in[3];
  char* ws = (char*)d_ws;

  __bf16* xo   = (__bf16*)(ws);               // 16,777,216 B (reused as attn-out after GEMM1)
  __bf16* wqo  = (__bf16*)(ws + 16777216);    //  6,291,456 B
  __bf16* wpo  = (__bf16*)(ws + 23068672);    //  2,097,152 B
  __bf16* qkv  = (__bf16*)(ws + 25165824);    // 50,331,648 B  [3][64][2048][64]
  __bf16* aout = xo;                          // reuse region 0
  float* y = (float*)d_out;

  cast_to_bf16<<<12288, 256, 0, stream>>>(x, wq, wp, xo, wqo, wpo);
  gemm_bt<0><<<dim3(64, 24), 256, 0, stream>>>(xo, wqo, qkv, nullptr, nullptr);
  mhsa_attn<<<dim3(64, 32), 256, 0, stream>>>(qkv, aout);
  gemm_bt<1><<<dim3(64, 8), 256, 0, stream>>>(aout, wpo, nullptr, y, bp);
}

// Round 3
// 221.897 us; speedup vs baseline: 1.4257x; 1.4257x over previous
//
#include <hip/hip_runtime.h>

// MHSA: B=4, N=2048, C=1024, H=16, HD=64
// cast(f32->bf16) -> GEMM1 (qkv, Q pre-scaled by 0.125*log2e) -> flash attn (swapped 32x32) -> GEMM2 (+bias)

typedef float f32x4 __attribute__((ext_vector_type(4)));
typedef float f32x16 __attribute__((ext_vector_type(16)));
typedef __bf16 bf16x8 __attribute__((ext_vector_type(8)));
typedef __bf16 bf16x4 __attribute__((ext_vector_type(4)));
typedef __bf16 bf16x2 __attribute__((ext_vector_type(2)));
typedef unsigned int u32;
typedef unsigned int u32x2 __attribute__((ext_vector_type(2)));

__device__ __forceinline__ void async16(const void* g, void* l) {
  __builtin_amdgcn_global_load_lds((const __attribute__((address_space(1))) unsigned int*)g,
                                   (__attribute__((address_space(3))) unsigned int*)l, 16, 0, 0);
}
__device__ __forceinline__ u32 cvtpk_bf16(float lo, float hi) {
  u32 r;
  asm("v_cvt_pk_bf16_f32 %0, %1, %2" : "=v"(r) : "v"(lo), "v"(hi));
  return r;
}
// v_permlane32_swap_b32 a, b : a.row1 <-> b.row0 (rows = 32-lane halves).
// Only used with DISTINCT source values (pa construction) — never self-swap.
__device__ __forceinline__ void swap32(u32& a, u32& b) {
  asm volatile("v_permlane32_swap_b32 %0, %1" : "+v"(a), "+v"(b));
}
__device__ __forceinline__ float xmax64(float x) { return fmaxf(x, __shfl_xor(x, 32, 64)); }
__device__ __forceinline__ float xsum64(float x) { return x + __shfl_xor(x, 32, 64); }
__device__ __forceinline__ float exp2v(float x) { return __builtin_amdgcn_exp2f(x); }

// ---------------- cast: x, w_qkv, w_proj f32 -> bf16 ----------------
__global__ __launch_bounds__(256) void cast_to_bf16(const float* __restrict__ x,
                                                    const float* __restrict__ wq,
                                                    const float* __restrict__ wp,
                                                    __bf16* __restrict__ xo,
                                                    __bf16* __restrict__ wqo,
                                                    __bf16* __restrict__ wpo) {
  long i = (long)blockIdx.x * 256 + threadIdx.x;
  const float* s; __bf16* d; long j;
  if (i < 2097152L)      { s = x;  d = xo;  j = i; }
  else if (i < 2883584L) { s = wq; d = wqo; j = i - 2097152L; }
  else                   { s = wp; d = wpo; j = i - 2883584L; }
  float4 v = ((const float4*)s)[j];
  bf16x4 o = { (__bf16)v.x, (__bf16)v.y, (__bf16)v.z, (__bf16)v.w };
  ((bf16x4*)d)[j] = o;
}

// ---------------- GEMM (B^T), m97 structure (verified R1) ----------------
template <int EPI>
__global__ __launch_bounds__(256) void gemm_bt(const __bf16* __restrict__ A,
                                               const __bf16* __restrict__ Bw,
                                               __bf16* __restrict__ Oq,
                                               float* __restrict__ Of,
                                               const float* __restrict__ bias) {
  const int tid = threadIdx.x;
  const int lane = tid & 63, w = tid >> 6;
  const int arow = lane & 15, agrp = lane >> 4;
  const int wm = w >> 1, wn = w & 1;
  const int bm = blockIdx.x, bn = blockIdx.y;
  __shared__ __bf16 As[128 * 32];
  __shared__ __bf16 Bs[128 * 32];
  f32x4 acc[4][4] = {};

  const int c0 = tid, c1 = tid + 256;
  const __bf16* Ag0 = A + ((size_t)(bm * 128 + (c0 >> 2)) << 10) + (c0 & 3) * 8;
  const __bf16* Ag1 = A + ((size_t)(bm * 128 + (c1 >> 2)) << 10) + (c1 & 3) * 8;
  const __bf16* Bg0 = Bw + ((size_t)(bn * 128 + (c0 >> 2)) << 10) + (c0 & 3) * 8;
  const __bf16* Bg1 = Bw + ((size_t)(bn * 128 + (c1 >> 2)) << 10) + (c1 & 3) * 8;

  for (int kt = 0; kt < 1024; kt += 32) {
    async16(Ag0 + kt, &As[c0 * 8]);
    async16(Ag1 + kt, &As[c1 * 8]);
    async16(Bg0 + kt, &Bs[c0 * 8]);
    async16(Bg1 + kt, &Bs[c1 * 8]);
    __syncthreads();
    bf16x8 af[4], bfr[4];
#pragma unroll
    for (int mi = 0; mi < 4; ++mi)
      af[mi] = *(const bf16x8*)&As[(wm * 64 + mi * 16 + arow) * 32 + agrp * 8];
#pragma unroll
    for (int ni = 0; ni < 4; ++ni)
      bfr[ni] = *(const bf16x8*)&Bs[(wn * 64 + ni * 16 + arow) * 32 + agrp * 8];
#pragma unroll
    for (int mi = 0; mi < 4; ++mi)
#pragma unroll
      for (int ni = 0; ni < 4; ++ni)
        acc[mi][ni] = __builtin_amdgcn_mfma_f32_16x16x32_bf16(af[mi], bfr[ni], acc[mi][ni], 0, 0, 0);
    __syncthreads();
  }

  const int rowb = bm * 128 + wm * 64 + agrp * 4;
  const int colb = bn * 128 + wn * 64 + arow;
  if (EPI == 0) {
#pragma unroll
    for (int mi = 0; mi < 4; ++mi) {
      const int row = rowb + mi * 16;
      const int bidx = row >> 11;
#pragma unroll
      for (int ni = 0; ni < 4; ++ni) {
        f32x4 v = acc[mi][ni];
        const int col = colb + ni * 16;
        const int which = col >> 10;
        const int h = (col >> 6) & 15;
        const int hd = col & 63;
        // Q pre-scale: 0.125 * log2(e) so attn softmax runs in exp2 domain
        const float s = (which == 0) ? 0.18033688011112042f : 1.0f;
        __bf16* dst = Oq + ((size_t)which * 64 + bidx * 16 + h) * (size_t)(2048 * 64) + hd;
#pragma unroll
        for (int i = 0; i < 4; ++i)
          dst[(size_t)((row + i) & 2047) * 64] = (__bf16)(v[i] * s);
      }
    }
  } else {
#pragma unroll
    for (int mi = 0; mi < 4; ++mi) {
      const int row = rowb + mi * 16;
#pragma unroll
      for (int ni = 0; ni < 4; ++ni) {
        const int col = colb + ni * 16;
        const float bv = bias[col];
        f32x4 v = acc[mi][ni];
#pragma unroll
        for (int i = 0; i < 4; ++i)
          Of[(size_t)(row + i) * 1024 + col] = v[i] + bv;
      }
    }
  }
}

// ---------------- flash attention, swapped-QK^T 32x32, in-register softmax ----------------
// QKV: [3][64 bh][2048][64] bf16 (Q pre-scaled by 0.125*log2e). Out: [4][2048][1024] bf16.
// 256 thr / 4 waves; wave owns 32 q-rows; KVBLK=64.
// ST[key][q] = mfma(A=K, B=Q): q lane-local (col=lane&31).
// OT[d][q]  = mfma(A=V^T, B=P^T): rescale/div per-lane scalars. P^T frags via cvt_pk+permlane (T12).
__global__ __launch_bounds__(256) void mhsa_attn(const __bf16* __restrict__ QKV,
                                                 __bf16* __restrict__ Out) {
  const int tid = threadIdx.x;
  const int lane = tid & 63, w = tid >> 6;
  const int blk = blockIdx.x;           // blk = qt*64 + bh -> XCD(blk%8)=bh%8: KV L2-resident per XCD
  const int bh = blk & 63, qt = blk >> 6;
  const int lq = lane & 31, hi = lane >> 5;
  const int l7 = lane & 7;

  const size_t bhoff = (size_t)bh * (2048 * 64);
  const __bf16* Qp = QKV + bhoff;
  const __bf16* Kp = QKV + (size_t)(64 * 2048 * 64) + bhoff;
  const __bf16* Vp = QKV + (size_t)(128 * 2048 * 64) + bhoff;

  __shared__ char smem[16384];
  char* KsB = smem;         // 8KB: K [64 key][64 d] bf16, byte ^= (key&7)<<4
  char* VTB = smem + 8192;  // 8KB: V^T [64 d][64 key] bf16, byte ^= (d&7)<<4

  const int q0 = qt * 128 + w * 32;

  // Q fragments (B-operand of 32x32x16): lane holds Q[q0+lq][s*16 + hi*8 + 0..7]
  bf16x8 qf[4];
#pragma unroll
  for (int s = 0; s < 4; ++s)
    qf[s] = *(const bf16x8*)&Qp[(size_t)(q0 + lq) * 64 + s * 16 + hi * 8];

  f32x16 Oacc0 = 0.f, Oacc1 = 0.f;   // OT: col=lane&31=q, d(per 32-blk)=(r&3)+8*(r>>2)+4*hi
  float m_run = -1e30f, l_run = 0.f;

  // K staging (R1-verified reg->LDS, swizzled writes): 256 thr cover rows 0..63
  const int kr0 = tid >> 3, kc8 = tid & 7;
  const int kr1 = kr0 + 32;
  // V staging (R1-verified transpose): d-chunk = tid>>5, key pair = (tid&31)*2
  const int c8v = tid >> 5, k0v = (tid & 31) * 2;

  for (int kt = 0; kt < 2048; kt += 64) {
    bf16x8 kv0 = *(const bf16x8*)&Kp[(size_t)(kt + kr0) * 64 + kc8 * 8];
    bf16x8 kv1 = *(const bf16x8*)&Kp[(size_t)(kt + kr1) * 64 + kc8 * 8];
    bf16x8 v0 = *(const bf16x8*)&Vp[(size_t)(kt + k0v) * 64 + c8v * 8];
    bf16x8 v1 = *(const bf16x8*)&Vp[(size_t)(kt + k0v + 1) * 64 + c8v * 8];
    *(bf16x8*)(KsB + ((kr0 * 128 + kc8 * 16) ^ ((kr0 & 7) << 4))) = kv0;
    *(bf16x8*)(KsB + ((kr1 * 128 + kc8 * 16) ^ ((kr1 & 7) << 4))) = kv1;
#pragma unroll
    for (int j = 0; j < 8; ++j) {
      const int d = c8v * 8 + j;
      bf16x2 pr = { v0[j], v1[j] };
      *(bf16x2*)(VTB + ((d * 128 + k0v * 2) ^ ((d & 7) << 4))) = pr;
    }
    __syncthreads();

    // ---- S^T = K Q^T : 8 MFMA ----
    f32x16 st0 = 0.f, st1 = 0.f;
#pragma unroll
    for (int s = 0; s < 4; ++s) {
      bf16x8 kf = *(const bf16x8*)(KsB + lq * 128 + ((s * 32 + hi * 16) ^ (l7 << 4)));
      st0 = __builtin_amdgcn_mfma_f32_32x32x16_bf16(kf, qf[s], st0, 0, 0, 0);
    }
#pragma unroll
    for (int s = 0; s < 4; ++s) {
      bf16x8 kf = *(const bf16x8*)(KsB + (32 + lq) * 128 + ((s * 32 + hi * 16) ^ (l7 << 4)));
      st1 = __builtin_amdgcn_mfma_f32_32x32x16_bf16(kf, qf[s], st1, 0, 0, 0);
    }

    // ---- online softmax, log2 domain, per-lane (q = lane&31) ----
    float mx = st0[0];
#pragma unroll
    for (int r = 1; r < 16; ++r) mx = fmaxf(mx, st0[r]);
#pragma unroll
    for (int r = 0; r < 16; ++r) mx = fmaxf(mx, st1[r]);
    mx = xmax64(mx);
    const float mnew = fmaxf(m_run, mx);
    const float fs = exp2v(m_run - mnew);
    m_run = mnew;
    float ssum = 0.f;
#pragma unroll
    for (int r = 0; r < 16; ++r) { st0[r] = exp2v(st0[r] - mnew); ssum += st0[r]; }
#pragma unroll
    for (int r = 0; r < 16; ++r) { st1[r] = exp2v(st1[r] - mnew); ssum += st1[r]; }
    ssum = xsum64(ssum);
    l_run = l_run * fs + ssum;
#pragma unroll
    for (int r = 0; r < 16; ++r) { Oacc0[r] *= fs; Oacc1[r] *= fs; }

    // ---- P -> bf16 B-operand frags in-register (T12; guide-verified pairing) ----
    // pa[ks][j] = P[q=lq][key = ks*16 + hi*8 + j]
    bf16x8 pa[4];
#pragma unroll
    for (int kb = 0; kb < 2; ++kb) {
      const f32x16& st = kb ? st1 : st0;
#pragma unroll
      for (int s16 = 0; s16 < 2; ++s16) {
        u32 A0 = cvtpk_bf16(st[8 * s16 + 0], st[8 * s16 + 1]);
        u32 B0 = cvtpk_bf16(st[8 * s16 + 4], st[8 * s16 + 5]);
        swap32(A0, B0);
        u32 A1 = cvtpk_bf16(st[8 * s16 + 2], st[8 * s16 + 3]);
        u32 B1 = cvtpk_bf16(st[8 * s16 + 6], st[8 * s16 + 7]);
        swap32(A1, B1);
        union { u32 wv[4]; bf16x8 v; } uu;
        uu.wv[0] = A0; uu.wv[1] = A1; uu.wv[2] = B0; uu.wv[3] = B1;
        pa[kb * 2 + s16] = uu.v;
      }
    }

    // ---- O^T += V^T P^T : 8 MFMA ----
#pragma unroll
    for (int ks = 0; ks < 4; ++ks) {
      bf16x8 vf = *(const bf16x8*)(VTB + lq * 128 + ((ks * 32 + hi * 16) ^ (l7 << 4)));
      Oacc0 = __builtin_amdgcn_mfma_f32_32x32x16_bf16(vf, pa[ks], Oacc0, 0, 0, 0);
    }
#pragma unroll
    for (int ks = 0; ks < 4; ++ks) {
      bf16x8 vf = *(const bf16x8*)(VTB + (32 + lq) * 128 + ((ks * 32 + hi * 16) ^ (l7 << 4)));
      Oacc1 = __builtin_amdgcn_mfma_f32_32x32x16_bf16(vf, pa[ks], Oacc1, 0, 0, 0);
    }
    __syncthreads();
  }

  // ---- epilogue: direct packed stores. lane (lq,hi) owns q=q0+lq, d = db*32 + rg*8 + hi*4 + 0..3
  const float inv = 1.0f / l_run;
  const int b = bh >> 4, h = bh & 15;
  __bf16* orow = Out + ((size_t)(b * 2048 + q0 + lq)) * 1024 + h * 64;
#pragma unroll
  for (int db = 0; db < 2; ++db) {
    const f32x16& O = db ? Oacc1 : Oacc0;
#pragma unroll
    for (int rg = 0; rg < 4; ++rg) {
      u32 plo = cvtpk_bf16(O[rg * 4 + 0] * inv, O[rg * 4 + 1] * inv);
      u32 phi = cvtpk_bf16(O[rg * 4 + 2] * inv, O[rg * 4 + 3] * inv);
      u32x2 pk = { plo, phi };
      *(u32x2*)&orow[db * 32 + rg * 8 + hi * 4] = pk;
    }
  }
}

// ---------------- launcher ----------------
extern "C" void kernel_launch(void* const* d_in, const int* in_sizes, int n_in,
                              void* d_out, int out_size, void* d_ws, size_t ws_size,
                              hipStream_t stream) {
  const float* x  = (const float*)d_in[0];
  const float* wq = (const float*)d_in[1];
  const float* wp = (const float*)d_in[2];
  const float* bp = (const float*)d_in[3];
  char* ws = (char*)d_ws;

  __bf16* xo   = (__bf16*)(ws);               // 16 MB (reused as attn-out)
  __bf16* wqo  = (__bf16*)(ws + 16777216);
  __bf16* wpo  = (__bf16*)(ws + 23068672);
  __bf16* qkv  = (__bf16*)(ws + 25165824);    // 48 MB [3][64][2048][64]
  __bf16* aout = xo;
  float* y = (float*)d_out;

  cast_to_bf16<<<12288, 256, 0, stream>>>(x, wq, wp, xo, wqo, wpo);
  gemm_bt<0><<<dim3(64, 24), 256, 0, stream>>>(xo, wqo, qkv, nullptr, nullptr);
  mhsa_attn<<<1024, 256, 0, stream>>>(qkv, aout);
  gemm_bt<1><<<dim3(64, 8), 256, 0, stream>>>(aout, wpo, nullptr, y, bp);
}

// Round 4
// 215.914 us; speedup vs baseline: 1.4652x; 1.0277x over previous
//
#include <hip/hip_runtime.h>

// MHSA: B=4, N=2048, C=1024, H=16, HD=64
// cast(f32->bf16) -> GEMM1 (qkv, Q pre-scaled by 0.125*log2e) -> flash attn (swapped 32x32) -> GEMM2 (+bias)

typedef float f32x2 __attribute__((ext_vector_type(2)));
typedef float f32x4 __attribute__((ext_vector_type(4)));
typedef float f32x16 __attribute__((ext_vector_type(16)));
typedef __bf16 bf16x8 __attribute__((ext_vector_type(8)));
typedef __bf16 bf16x4 __attribute__((ext_vector_type(4)));
typedef __bf16 bf16x2 __attribute__((ext_vector_type(2)));
typedef unsigned int u32;
typedef unsigned int u32x2 __attribute__((ext_vector_type(2)));

__device__ __forceinline__ void async16(const void* g, void* l) {
  __builtin_amdgcn_global_load_lds((const __attribute__((address_space(1))) unsigned int*)g,
                                   (__attribute__((address_space(3))) unsigned int*)l, 16, 0, 0);
}
__device__ __forceinline__ u32 cvtpk_bf16(float lo, float hi) {
  u32 r;
  asm("v_cvt_pk_bf16_f32 %0, %1, %2" : "=v"(r) : "v"(lo), "v"(hi));
  return r;
}
// v_permlane32_swap_b32 a, b : a.row1 <-> b.row0. Only with DISTINCT sources.
__device__ __forceinline__ void swap32(u32& a, u32& b) {
  asm volatile("v_permlane32_swap_b32 %0, %1" : "+v"(a), "+v"(b));
}
__device__ __forceinline__ float xmax64(float x) { return fmaxf(x, __shfl_xor(x, 32, 64)); }
__device__ __forceinline__ float xsum64(float x) { return x + __shfl_xor(x, 32, 64); }
__device__ __forceinline__ float exp2v(float x) { return __builtin_amdgcn_exp2f(x); }
__device__ __forceinline__ f32x2 pkmax(f32x2 a, f32x2 b) {
  return f32x2{ fmaxf(a.x, b.x), fmaxf(a.y, b.y) };
}

// ---------------- cast: x, w_qkv, w_proj f32 -> bf16 ----------------
__global__ __launch_bounds__(256) void cast_to_bf16(const float* __restrict__ x,
                                                    const float* __restrict__ wq,
                                                    const float* __restrict__ wp,
                                                    __bf16* __restrict__ xo,
                                                    __bf16* __restrict__ wqo,
                                                    __bf16* __restrict__ wpo) {
  long i = (long)blockIdx.x * 256 + threadIdx.x;
  const float* s; __bf16* d; long j;
  if (i < 2097152L)      { s = x;  d = xo;  j = i; }
  else if (i < 2883584L) { s = wq; d = wqo; j = i - 2097152L; }
  else                   { s = wp; d = wpo; j = i - 2883584L; }
  float4 v = ((const float4*)s)[j];
  bf16x4 o = { (__bf16)v.x, (__bf16)v.y, (__bf16)v.z, (__bf16)v.w };
  ((bf16x4*)d)[j] = o;
}

// ---------------- GEMM (B^T), m97 structure (verified R1/R3) ----------------
template <int EPI>
__global__ __launch_bounds__(256) void gemm_bt(const __bf16* __restrict__ A,
                                               const __bf16* __restrict__ Bw,
                                               __bf16* __restrict__ Oq,
                                               float* __restrict__ Of,
                                               const float* __restrict__ bias) {
  const int tid = threadIdx.x;
  const int lane = tid & 63, w = tid >> 6;
  const int arow = lane & 15, agrp = lane >> 4;
  const int wm = w >> 1, wn = w & 1;
  const int bm = blockIdx.x, bn = blockIdx.y;
  __shared__ __bf16 As[128 * 32];
  __shared__ __bf16 Bs[128 * 32];
  f32x4 acc[4][4] = {};

  const int c0 = tid, c1 = tid + 256;
  const __bf16* Ag0 = A + ((size_t)(bm * 128 + (c0 >> 2)) << 10) + (c0 & 3) * 8;
  const __bf16* Ag1 = A + ((size_t)(bm * 128 + (c1 >> 2)) << 10) + (c1 & 3) * 8;
  const __bf16* Bg0 = Bw + ((size_t)(bn * 128 + (c0 >> 2)) << 10) + (c0 & 3) * 8;
  const __bf16* Bg1 = Bw + ((size_t)(bn * 128 + (c1 >> 2)) << 10) + (c1 & 3) * 8;

  for (int kt = 0; kt < 1024; kt += 32) {
    async16(Ag0 + kt, &As[c0 * 8]);
    async16(Ag1 + kt, &As[c1 * 8]);
    async16(Bg0 + kt, &Bs[c0 * 8]);
    async16(Bg1 + kt, &Bs[c1 * 8]);
    __syncthreads();
    bf16x8 af[4], bfr[4];
#pragma unroll
    for (int mi = 0; mi < 4; ++mi)
      af[mi] = *(const bf16x8*)&As[(wm * 64 + mi * 16 + arow) * 32 + agrp * 8];
#pragma unroll
    for (int ni = 0; ni < 4; ++ni)
      bfr[ni] = *(const bf16x8*)&Bs[(wn * 64 + ni * 16 + arow) * 32 + agrp * 8];
#pragma unroll
    for (int mi = 0; mi < 4; ++mi)
#pragma unroll
      for (int ni = 0; ni < 4; ++ni)
        acc[mi][ni] = __builtin_amdgcn_mfma_f32_16x16x32_bf16(af[mi], bfr[ni], acc[mi][ni], 0, 0, 0);
    __syncthreads();
  }

  const int rowb = bm * 128 + wm * 64 + agrp * 4;
  const int colb = bn * 128 + wn * 64 + arow;
  if (EPI == 0) {
#pragma unroll
    for (int mi = 0; mi < 4; ++mi) {
      const int row = rowb + mi * 16;
      const int bidx = row >> 11;
#pragma unroll
      for (int ni = 0; ni < 4; ++ni) {
        f32x4 v = acc[mi][ni];
        const int col = colb + ni * 16;
        const int which = col >> 10;
        const int h = (col >> 6) & 15;
        const int hd = col & 63;
        // Q pre-scale: 0.125 * log2(e) so attn softmax runs in exp2 domain
        const float s = (which == 0) ? 0.18033688011112042f : 1.0f;
        __bf16* dst = Oq + ((size_t)which * 64 + bidx * 16 + h) * (size_t)(2048 * 64) + hd;
#pragma unroll
        for (int i = 0; i < 4; ++i)
          dst[(size_t)((row + i) & 2047) * 64] = (__bf16)(v[i] * s);
      }
    }
  } else {
#pragma unroll
    for (int mi = 0; mi < 4; ++mi) {
      const int row = rowb + mi * 16;
#pragma unroll
      for (int ni = 0; ni < 4; ++ni) {
        const int col = colb + ni * 16;
        const float bv = bias[col];
        f32x4 v = acc[mi][ni];
#pragma unroll
        for (int i = 0; i < 4; ++i)
          Of[(size_t)(row + i) * 1024 + col] = v[i] + bv;
      }
    }
  }
}

// ---------------- flash attention, swapped-QK^T 32x32, in-register softmax ----------------
// R4: + defer-max (T13, THR=8 log2-domain), packed-f32 softmax trees, setprio (T5).
__global__ __launch_bounds__(256) void mhsa_attn(const __bf16* __restrict__ QKV,
                                                 __bf16* __restrict__ Out) {
  const int tid = threadIdx.x;
  const int lane = tid & 63, w = tid >> 6;
  const int blk = blockIdx.x;           // blk = qt*64 + bh -> XCD(blk%8)=bh%8: KV L2-resident per XCD
  const int bh = blk & 63, qt = blk >> 6;
  const int lq = lane & 31, hi = lane >> 5;
  const int l7 = lane & 7;

  const size_t bhoff = (size_t)bh * (2048 * 64);
  const __bf16* Qp = QKV + bhoff;
  const __bf16* Kp = QKV + (size_t)(64 * 2048 * 64) + bhoff;
  const __bf16* Vp = QKV + (size_t)(128 * 2048 * 64) + bhoff;

  __shared__ char smem[16384];
  char* KsB = smem;         // 8KB: K [64 key][64 d] bf16, byte ^= (key&7)<<4
  char* VTB = smem + 8192;  // 8KB: V^T [64 d][64 key] bf16, byte ^= (d&7)<<4

  const int q0 = qt * 128 + w * 32;

  bf16x8 qf[4];
#pragma unroll
  for (int s = 0; s < 4; ++s)
    qf[s] = *(const bf16x8*)&Qp[(size_t)(q0 + lq) * 64 + s * 16 + hi * 8];

  f32x16 Oacc0 = 0.f, Oacc1 = 0.f;   // OT: col=lane&31=q, d(per 32-blk)=(r&3)+8*(r>>2)+4*hi
  float m_run = -1e30f, l_run = 0.f;

  const int kr0 = tid >> 3, kc8 = tid & 7;
  const int kr1 = kr0 + 32;
  const int c8v = tid >> 5, k0v = (tid & 31) * 2;

  for (int kt = 0; kt < 2048; kt += 64) {
    bf16x8 kv0 = *(const bf16x8*)&Kp[(size_t)(kt + kr0) * 64 + kc8 * 8];
    bf16x8 kv1 = *(const bf16x8*)&Kp[(size_t)(kt + kr1) * 64 + kc8 * 8];
    bf16x8 v0 = *(const bf16x8*)&Vp[(size_t)(kt + k0v) * 64 + c8v * 8];
    bf16x8 v1 = *(const bf16x8*)&Vp[(size_t)(kt + k0v + 1) * 64 + c8v * 8];
    *(bf16x8*)(KsB + ((kr0 * 128 + kc8 * 16) ^ ((kr0 & 7) << 4))) = kv0;
    *(bf16x8*)(KsB + ((kr1 * 128 + kc8 * 16) ^ ((kr1 & 7) << 4))) = kv1;
#pragma unroll
    for (int j = 0; j < 8; ++j) {
      const int d = c8v * 8 + j;
      bf16x2 pr = { v0[j], v1[j] };
      *(bf16x2*)(VTB + ((d * 128 + k0v * 2) ^ ((d & 7) << 4))) = pr;
    }
    __syncthreads();

    // ---- S^T = K Q^T : 8 MFMA (T5: setprio around cluster) ----
    f32x16 st0 = 0.f, st1 = 0.f;
    __builtin_amdgcn_s_setprio(1);
#pragma unroll
    for (int s = 0; s < 4; ++s) {
      bf16x8 kf = *(const bf16x8*)(KsB + lq * 128 + ((s * 32 + hi * 16) ^ (l7 << 4)));
      st0 = __builtin_amdgcn_mfma_f32_32x32x16_bf16(kf, qf[s], st0, 0, 0, 0);
    }
#pragma unroll
    for (int s = 0; s < 4; ++s) {
      bf16x8 kf = *(const bf16x8*)(KsB + (32 + lq) * 128 + ((s * 32 + hi * 16) ^ (l7 << 4)));
      st1 = __builtin_amdgcn_mfma_f32_32x32x16_bf16(kf, qf[s], st1, 0, 0, 0);
    }
    __builtin_amdgcn_s_setprio(0);

    // ---- online softmax, log2 domain, packed-f32 trees ----
    f32x2 m2 = f32x2{ st0[0], st0[1] };
#pragma unroll
    for (int r = 1; r < 8; ++r) m2 = pkmax(m2, f32x2{ st0[2 * r], st0[2 * r + 1] });
#pragma unroll
    for (int r = 0; r < 8; ++r) m2 = pkmax(m2, f32x2{ st1[2 * r], st1[2 * r + 1] });
    float mx = xmax64(fmaxf(m2.x, m2.y));

    // defer-max (T13): rescale only when max grew past THR=8 (P bounded by 2^8)
    if (!__all(mx - m_run <= 8.f)) {
      const float mnew = fmaxf(m_run, mx);
      const float fs = exp2v(m_run - mnew);
      m_run = mnew;
      l_run *= fs;
#pragma unroll
      for (int r = 0; r < 16; ++r) { Oacc0[r] *= fs; Oacc1[r] *= fs; }
    }

    // P = exp2(S - m_run); sum via packed adds
    const float mb = m_run;
#pragma unroll
    for (int r = 0; r < 16; ++r) st0[r] = exp2v(st0[r] - mb);
#pragma unroll
    for (int r = 0; r < 16; ++r) st1[r] = exp2v(st1[r] - mb);
    f32x2 s2 = f32x2{ st0[0], st0[1] };
#pragma unroll
    for (int r = 1; r < 8; ++r) s2 += f32x2{ st0[2 * r], st0[2 * r + 1] };
#pragma unroll
    for (int r = 0; r < 8; ++r) s2 += f32x2{ st1[2 * r], st1[2 * r + 1] };
    l_run += xsum64(s2.x + s2.y);

    // ---- P -> bf16 B-operand frags in-register (T12) ----
    // pa[ks][j] = P[q=lq][key = ks*16 + hi*8 + j]
    bf16x8 pa[4];
#pragma unroll
    for (int kb = 0; kb < 2; ++kb) {
      const f32x16& st = kb ? st1 : st0;
#pragma unroll
      for (int s16 = 0; s16 < 2; ++s16) {
        u32 A0 = cvtpk_bf16(st[8 * s16 + 0], st[8 * s16 + 1]);
        u32 B0 = cvtpk_bf16(st[8 * s16 + 4], st[8 * s16 + 5]);
        swap32(A0, B0);
        u32 A1 = cvtpk_bf16(st[8 * s16 + 2], st[8 * s16 + 3]);
        u32 B1 = cvtpk_bf16(st[8 * s16 + 6], st[8 * s16 + 7]);
        swap32(A1, B1);
        union { u32 wv[4]; bf16x8 v; } uu;
        uu.wv[0] = A0; uu.wv[1] = A1; uu.wv[2] = B0; uu.wv[3] = B1;
        pa[kb * 2 + s16] = uu.v;
      }
    }

    // ---- O^T += V^T P^T : 8 MFMA (T5) ----
    __builtin_amdgcn_s_setprio(1);
#pragma unroll
    for (int ks = 0; ks < 4; ++ks) {
      bf16x8 vf = *(const bf16x8*)(VTB + lq * 128 + ((ks * 32 + hi * 16) ^ (l7 << 4)));
      Oacc0 = __builtin_amdgcn_mfma_f32_32x32x16_bf16(vf, pa[ks], Oacc0, 0, 0, 0);
    }
#pragma unroll
    for (int ks = 0; ks < 4; ++ks) {
      bf16x8 vf = *(const bf16x8*)(VTB + (32 + lq) * 128 + ((ks * 32 + hi * 16) ^ (l7 << 4)));
      Oacc1 = __builtin_amdgcn_mfma_f32_32x32x16_bf16(vf, pa[ks], Oacc1, 0, 0, 0);
    }
    __builtin_amdgcn_s_setprio(0);
    __syncthreads();
  }

  // ---- epilogue: lane (lq,hi) owns q=q0+lq, d = db*32 + rg*8 + hi*4 + 0..3 ----
  const float inv = 1.0f / l_run;
  const int b = bh >> 4, h = bh & 15;
  __bf16* orow = Out + ((size_t)(b * 2048 + q0 + lq)) * 1024 + h * 64;
#pragma unroll
  for (int db = 0; db < 2; ++db) {
    const f32x16& O = db ? Oacc1 : Oacc0;
#pragma unroll
    for (int rg = 0; rg < 4; ++rg) {
      u32 plo = cvtpk_bf16(O[rg * 4 + 0] * inv, O[rg * 4 + 1] * inv);
      u32 phi = cvtpk_bf16(O[rg * 4 + 2] * inv, O[rg * 4 + 3] * inv);
      u32x2 pk = { plo, phi };
      *(u32x2*)&orow[db * 32 + rg * 8 + hi * 4] = pk;
    }
  }
}

// ---------------- launcher ----------------
extern "C" void kernel_launch(void* const* d_in, const int* in_sizes, int n_in,
                              void* d_out, int out_size, void* d_ws, size_t ws_size,
                              hipStream_t stream) {
  const float* x  = (const float*)d_in[0];
  const float* wq = (const float*)d_in[1];
  const float* wp = (const float*)d_in[2];
  const float* bp = (const float*)d_in[3];
  char* ws = (char*)d_ws;

  __bf16* xo   = (__bf16*)(ws);               // 16 MB (reused as attn-out)
  __bf16* wqo  = (__bf16*)(ws + 16777216);
  __bf16* wpo  = (__bf16*)(ws + 23068672);
  __bf16* qkv  = (__bf16*)(ws + 25165824);    // 48 MB [3][64][2048][64]
  __bf16* aout = xo;
  float* y = (float*)d_out;

  cast_to_bf16<<<12288, 256, 0, stream>>>(x, wq, wp, xo, wqo, wpo);
  gemm_bt<0><<<dim3(64, 24), 256, 0, stream>>>(xo, wqo, qkv, nullptr, nullptr);
  mhsa_attn<<<1024, 256, 0, stream>>>(qkv, aout);
  gemm_bt<1><<<dim3(64, 8), 256, 0, stream>>>(aout, wpo, nullptr, y, bp);
}

// Round 5
// 202.366 us; speedup vs baseline: 1.5633x; 1.0670x over previous
//
#include <hip/hip_runtime.h>

// MHSA: B=4, N=2048, C=1024, H=16, HD=64
// cast(f32->bf16) -> GEMM1 (qkv, Q pre-scaled by 0.125*log2e) -> flash attn (swapped 32x32) -> GEMM2 (+bias)

typedef float f32x2 __attribute__((ext_vector_type(2)));
typedef float f32x4 __attribute__((ext_vector_type(4)));
typedef float f32x16 __attribute__((ext_vector_type(16)));
typedef __bf16 bf16x8 __attribute__((ext_vector_type(8)));
typedef __bf16 bf16x4 __attribute__((ext_vector_type(4)));
typedef __bf16 bf16x2 __attribute__((ext_vector_type(2)));
typedef unsigned int u32;
typedef unsigned int u32x2 __attribute__((ext_vector_type(2)));

__device__ __forceinline__ void async16(const void* g, void* l) {
  __builtin_amdgcn_global_load_lds((const __attribute__((address_space(1))) unsigned int*)g,
                                   (__attribute__((address_space(3))) unsigned int*)l, 16, 0, 0);
}
__device__ __forceinline__ u32 cvtpk_bf16(float lo, float hi) {
  u32 r;
  asm("v_cvt_pk_bf16_f32 %0, %1, %2" : "=v"(r) : "v"(lo), "v"(hi));
  return r;
}
// v_permlane32_swap_b32 a, b : a.row1 <-> b.row0. Only with DISTINCT sources.
__device__ __forceinline__ void swap32(u32& a, u32& b) {
  asm volatile("v_permlane32_swap_b32 %0, %1" : "+v"(a), "+v"(b));
}
__device__ __forceinline__ float xmax64(float x) { return fmaxf(x, __shfl_xor(x, 32, 64)); }
__device__ __forceinline__ float xsum64(float x) { return x + __shfl_xor(x, 32, 64); }
__device__ __forceinline__ float exp2v(float x) { return __builtin_amdgcn_exp2f(x); }
__device__ __forceinline__ f32x2 pkmax(f32x2 a, f32x2 b) {
  return f32x2{ fmaxf(a.x, b.x), fmaxf(a.y, b.y) };
}

// ---------------- cast: x, w_qkv, w_proj f32 -> bf16 ----------------
__global__ __launch_bounds__(256) void cast_to_bf16(const float* __restrict__ x,
                                                    const float* __restrict__ wq,
                                                    const float* __restrict__ wp,
                                                    __bf16* __restrict__ xo,
                                                    __bf16* __restrict__ wqo,
                                                    __bf16* __restrict__ wpo) {
  long i = (long)blockIdx.x * 256 + threadIdx.x;
  const float* s; __bf16* d; long j;
  if (i < 2097152L)      { s = x;  d = xo;  j = i; }
  else if (i < 2883584L) { s = wq; d = wqo; j = i - 2097152L; }
  else                   { s = wp; d = wpo; j = i - 2883584L; }
  float4 v = ((const float4*)s)[j];
  bf16x4 o = { (__bf16)v.x, (__bf16)v.y, (__bf16)v.z, (__bf16)v.w };
  ((bf16x4*)d)[j] = o;
}

// ---------------- GEMM (B^T), m97 structure (verified R1/R3) ----------------
template <int EPI>
__global__ __launch_bounds__(256) void gemm_bt(const __bf16* __restrict__ A,
                                               const __bf16* __restrict__ Bw,
                                               __bf16* __restrict__ Oq,
                                               float* __restrict__ Of,
                                               const float* __restrict__ bias) {
  const int tid = threadIdx.x;
  const int lane = tid & 63, w = tid >> 6;
  const int arow = lane & 15, agrp = lane >> 4;
  const int wm = w >> 1, wn = w & 1;
  const int bm = blockIdx.x, bn = blockIdx.y;
  __shared__ __bf16 As[128 * 32];
  __shared__ __bf16 Bs[128 * 32];
  f32x4 acc[4][4] = {};

  const int c0 = tid, c1 = tid + 256;
  const __bf16* Ag0 = A + ((size_t)(bm * 128 + (c0 >> 2)) << 10) + (c0 & 3) * 8;
  const __bf16* Ag1 = A + ((size_t)(bm * 128 + (c1 >> 2)) << 10) + (c1 & 3) * 8;
  const __bf16* Bg0 = Bw + ((size_t)(bn * 128 + (c0 >> 2)) << 10) + (c0 & 3) * 8;
  const __bf16* Bg1 = Bw + ((size_t)(bn * 128 + (c1 >> 2)) << 10) + (c1 & 3) * 8;

  for (int kt = 0; kt < 1024; kt += 32) {
    async16(Ag0 + kt, &As[c0 * 8]);
    async16(Ag1 + kt, &As[c1 * 8]);
    async16(Bg0 + kt, &Bs[c0 * 8]);
    async16(Bg1 + kt, &Bs[c1 * 8]);
    __syncthreads();
    bf16x8 af[4], bfr[4];
#pragma unroll
    for (int mi = 0; mi < 4; ++mi)
      af[mi] = *(const bf16x8*)&As[(wm * 64 + mi * 16 + arow) * 32 + agrp * 8];
#pragma unroll
    for (int ni = 0; ni < 4; ++ni)
      bfr[ni] = *(const bf16x8*)&Bs[(wn * 64 + ni * 16 + arow) * 32 + agrp * 8];
#pragma unroll
    for (int mi = 0; mi < 4; ++mi)
#pragma unroll
      for (int ni = 0; ni < 4; ++ni)
        acc[mi][ni] = __builtin_amdgcn_mfma_f32_16x16x32_bf16(af[mi], bfr[ni], acc[mi][ni], 0, 0, 0);
    __syncthreads();
  }

  const int rowb = bm * 128 + wm * 64 + agrp * 4;
  const int colb = bn * 128 + wn * 64 + arow;
  if (EPI == 0) {
#pragma unroll
    for (int mi = 0; mi < 4; ++mi) {
      const int row = rowb + mi * 16;
      const int bidx = row >> 11;
#pragma unroll
      for (int ni = 0; ni < 4; ++ni) {
        f32x4 v = acc[mi][ni];
        const int col = colb + ni * 16;
        const int which = col >> 10;
        const int h = (col >> 6) & 15;
        const int hd = col & 63;
        // Q pre-scale: 0.125 * log2(e) so attn softmax runs in exp2 domain
        const float s = (which == 0) ? 0.18033688011112042f : 1.0f;
        __bf16* dst = Oq + ((size_t)which * 64 + bidx * 16 + h) * (size_t)(2048 * 64) + hd;
#pragma unroll
        for (int i = 0; i < 4; ++i)
          dst[(size_t)((row + i) & 2047) * 64] = (__bf16)(v[i] * s);
      }
    }
  } else {
#pragma unroll
    for (int mi = 0; mi < 4; ++mi) {
      const int row = rowb + mi * 16;
#pragma unroll
      for (int ni = 0; ni < 4; ++ni) {
        const int col = colb + ni * 16;
        const float bv = bias[col];
        f32x4 v = acc[mi][ni];
#pragma unroll
        for (int i = 0; i < 4; ++i)
          Of[(size_t)(row + i) * 1024 + col] = v[i] + bv;
      }
    }
  }
}

// ---------------- flash attention, swapped-QK^T 32x32, in-register softmax ----------------
// R5: double-buffered LDS + T14 async-STAGE split (issue loads early, write late),
//     single barrier per iteration. R4's defer-max/packed-trees/setprio retained.
__global__ __launch_bounds__(256) void mhsa_attn(const __bf16* __restrict__ QKV,
                                                 __bf16* __restrict__ Out) {
  const int tid = threadIdx.x;
  const int lane = tid & 63, w = tid >> 6;
  const int blk = blockIdx.x;           // blk = qt*64 + bh -> XCD(blk%8)=bh%8: KV L2-resident per XCD
  const int bh = blk & 63, qt = blk >> 6;
  const int lq = lane & 31, hi = lane >> 5;
  const int l7 = lane & 7;

  const size_t bhoff = (size_t)bh * (2048 * 64);
  const __bf16* Qp = QKV + bhoff;
  const __bf16* Kp = QKV + (size_t)(64 * 2048 * 64) + bhoff;
  const __bf16* Vp = QKV + (size_t)(128 * 2048 * 64) + bhoff;

  __shared__ char smem[32768];  // 2 x {K [64][64] swz (8KB) | V^T [64][64] swz (8KB)}

  const int q0 = qt * 128 + w * 32;

  bf16x8 qf[4];
#pragma unroll
  for (int s = 0; s < 4; ++s)
    qf[s] = *(const bf16x8*)&Qp[(size_t)(q0 + lq) * 64 + s * 16 + hi * 8];

  f32x16 Oacc0 = 0.f, Oacc1 = 0.f;   // OT: col=lane&31=q, d(per 32-blk)=(r&3)+8*(r>>2)+4*hi
  float m_run = -1e30f, l_run = 0.f;

  const int kr0 = tid >> 3, kc8 = tid & 7;
  const int kr1 = kr0 + 32;
  const int c8v = tid >> 5, k0v = (tid & 31) * 2;
  // precomputed swizzled LDS byte offsets (within a buffer)
  const int koff0 = (kr0 * 128 + kc8 * 16) ^ ((kr0 & 7) << 4);
  const int koff1 = (kr1 * 128 + kc8 * 16) ^ ((kr1 & 7) << 4);

  // ---- prologue: stage tile 0 into buf0 ----
  {
    bf16x8 kv0 = *(const bf16x8*)&Kp[(size_t)kr0 * 64 + kc8 * 8];
    bf16x8 kv1 = *(const bf16x8*)&Kp[(size_t)kr1 * 64 + kc8 * 8];
    bf16x8 v0 = *(const bf16x8*)&Vp[(size_t)k0v * 64 + c8v * 8];
    bf16x8 v1 = *(const bf16x8*)&Vp[(size_t)(k0v + 1) * 64 + c8v * 8];
    char* Kb = smem;
    char* Vb = smem + 8192;
    *(bf16x8*)(Kb + koff0) = kv0;
    *(bf16x8*)(Kb + koff1) = kv1;
#pragma unroll
    for (int j = 0; j < 8; ++j) {
      const int d = c8v * 8 + j;
      bf16x2 pr = { v0[j], v1[j] };
      *(bf16x2*)(Vb + ((d * 128 + k0v * 2) ^ ((d & 7) << 4))) = pr;
    }
  }
  __syncthreads();

  for (int t = 0; t < 32; ++t) {
    char* Kc = smem + (t & 1) * 16384;        // current K buffer
    char* Vc = Kc + 8192;                     // current V^T buffer
    char* Kn = smem + ((t & 1) ^ 1) * 16384;  // next K buffer
    char* Vn = Kn + 8192;

    // ---- T14 issue-early: global loads for tile t+1 (no wait; hidden under compute) ----
    bf16x8 kv0n, kv1n, v0n, v1n;
    const bool pf = (t < 31);
    if (pf) {
      const int ktn = (t + 1) * 64;
      kv0n = *(const bf16x8*)&Kp[(size_t)(ktn + kr0) * 64 + kc8 * 8];
      kv1n = *(const bf16x8*)&Kp[(size_t)(ktn + kr1) * 64 + kc8 * 8];
      v0n = *(const bf16x8*)&Vp[(size_t)(ktn + k0v) * 64 + c8v * 8];
      v1n = *(const bf16x8*)&Vp[(size_t)(ktn + k0v + 1) * 64 + c8v * 8];
    }

    // ---- S^T = K Q^T : 8 MFMA (T5) ----
    f32x16 st0 = 0.f, st1 = 0.f;
    __builtin_amdgcn_s_setprio(1);
#pragma unroll
    for (int s = 0; s < 4; ++s) {
      bf16x8 kf = *(const bf16x8*)(Kc + lq * 128 + ((s * 32 + hi * 16) ^ (l7 << 4)));
      st0 = __builtin_amdgcn_mfma_f32_32x32x16_bf16(kf, qf[s], st0, 0, 0, 0);
    }
#pragma unroll
    for (int s = 0; s < 4; ++s) {
      bf16x8 kf = *(const bf16x8*)(Kc + (32 + lq) * 128 + ((s * 32 + hi * 16) ^ (l7 << 4)));
      st1 = __builtin_amdgcn_mfma_f32_32x32x16_bf16(kf, qf[s], st1, 0, 0, 0);
    }
    __builtin_amdgcn_s_setprio(0);

    // ---- online softmax, log2 domain, packed-f32 trees ----
    f32x2 m2 = f32x2{ st0[0], st0[1] };
#pragma unroll
    for (int r = 1; r < 8; ++r) m2 = pkmax(m2, f32x2{ st0[2 * r], st0[2 * r + 1] });
#pragma unroll
    for (int r = 0; r < 8; ++r) m2 = pkmax(m2, f32x2{ st1[2 * r], st1[2 * r + 1] });
    float mx = xmax64(fmaxf(m2.x, m2.y));

    // defer-max (T13): rescale only when max grew past THR=8 (P bounded by 2^8)
    if (!__all(mx - m_run <= 8.f)) {
      const float mnew = fmaxf(m_run, mx);
      const float fs = exp2v(m_run - mnew);
      m_run = mnew;
      l_run *= fs;
#pragma unroll
      for (int r = 0; r < 16; ++r) { Oacc0[r] *= fs; Oacc1[r] *= fs; }
    }

    // P = exp2(S - m_run); sum via packed adds
    const float mb = m_run;
#pragma unroll
    for (int r = 0; r < 16; ++r) st0[r] = exp2v(st0[r] - mb);
#pragma unroll
    for (int r = 0; r < 16; ++r) st1[r] = exp2v(st1[r] - mb);
    f32x2 s2 = f32x2{ st0[0], st0[1] };
#pragma unroll
    for (int r = 1; r < 8; ++r) s2 += f32x2{ st0[2 * r], st0[2 * r + 1] };
#pragma unroll
    for (int r = 0; r < 8; ++r) s2 += f32x2{ st1[2 * r], st1[2 * r + 1] };
    l_run += xsum64(s2.x + s2.y);

    // ---- P -> bf16 B-operand frags in-register (T12) ----
    bf16x8 pa[4];
#pragma unroll
    for (int kb = 0; kb < 2; ++kb) {
      const f32x16& st = kb ? st1 : st0;
#pragma unroll
      for (int s16 = 0; s16 < 2; ++s16) {
        u32 A0 = cvtpk_bf16(st[8 * s16 + 0], st[8 * s16 + 1]);
        u32 B0 = cvtpk_bf16(st[8 * s16 + 4], st[8 * s16 + 5]);
        swap32(A0, B0);
        u32 A1 = cvtpk_bf16(st[8 * s16 + 2], st[8 * s16 + 3]);
        u32 B1 = cvtpk_bf16(st[8 * s16 + 6], st[8 * s16 + 7]);
        swap32(A1, B1);
        union { u32 wv[4]; bf16x8 v; } uu;
        uu.wv[0] = A0; uu.wv[1] = A1; uu.wv[2] = B0; uu.wv[3] = B1;
        pa[kb * 2 + s16] = uu.v;
      }
    }

    // ---- O^T += V^T P^T : 8 MFMA (T5) ----
    __builtin_amdgcn_s_setprio(1);
#pragma unroll
    for (int ks = 0; ks < 4; ++ks) {
      bf16x8 vf = *(const bf16x8*)(Vc + lq * 128 + ((ks * 32 + hi * 16) ^ (l7 << 4)));
      Oacc0 = __builtin_amdgcn_mfma_f32_32x32x16_bf16(vf, pa[ks], Oacc0, 0, 0, 0);
    }
#pragma unroll
    for (int ks = 0; ks < 4; ++ks) {
      bf16x8 vf = *(const bf16x8*)(Vc + (32 + lq) * 128 + ((ks * 32 + hi * 16) ^ (l7 << 4)));
      Oacc1 = __builtin_amdgcn_mfma_f32_32x32x16_bf16(vf, pa[ks], Oacc1, 0, 0, 0);
    }
    __builtin_amdgcn_s_setprio(0);

    // ---- T14 write-late: stage tile t+1 into the other buffer (vmcnt auto-inserted) ----
    if (pf) {
      *(bf16x8*)(Kn + koff0) = kv0n;
      *(bf16x8*)(Kn + koff1) = kv1n;
#pragma unroll
      for (int j = 0; j < 8; ++j) {
        const int d = c8v * 8 + j;
        bf16x2 pr = { v0n[j], v1n[j] };
        *(bf16x2*)(Vn + ((d * 128 + k0v * 2) ^ ((d & 7) << 4))) = pr;
      }
    }
    __syncthreads();
  }

  // ---- epilogue: lane (lq,hi) owns q=q0+lq, d = db*32 + rg*8 + hi*4 + 0..3 ----
  const float inv = 1.0f / l_run;
  const int b = bh >> 4, h = bh & 15;
  __bf16* orow = Out + ((size_t)(b * 2048 + q0 + lq)) * 1024 + h * 64;
#pragma unroll
  for (int db = 0; db < 2; ++db) {
    const f32x16& O = db ? Oacc1 : Oacc0;
#pragma unroll
    for (int rg = 0; rg < 4; ++rg) {
      u32 plo = cvtpk_bf16(O[rg * 4 + 0] * inv, O[rg * 4 + 1] * inv);
      u32 phi = cvtpk_bf16(O[rg * 4 + 2] * inv, O[rg * 4 + 3] * inv);
      u32x2 pk = { plo, phi };
      *(u32x2*)&orow[db * 32 + rg * 8 + hi * 4] = pk;
    }
  }
}

// ---------------- launcher ----------------
extern "C" void kernel_launch(void* const* d_in, const int* in_sizes, int n_in,
                              void* d_out, int out_size, void* d_ws, size_t ws_size,
                              hipStream_t stream) {
  const float* x  = (const float*)d_in[0];
  const float* wq = (const float*)d_in[1];
  const float* wp = (const float*)d_in[2];
  const float* bp = (const float*)d_in[3];
  char* ws = (char*)d_ws;

  __bf16* xo   = (__bf16*)(ws);               // 16 MB (reused as attn-out)
  __bf16* wqo  = (__bf16*)(ws + 16777216);
  __bf16* wpo  = (__bf16*)(ws + 23068672);
  __bf16* qkv  = (__bf16*)(ws + 25165824);    // 48 MB [3][64][2048][64]
  __bf16* aout = xo;
  float* y = (float*)d_out;

  cast_to_bf16<<<12288, 256, 0, stream>>>(x, wq, wp, xo, wqo, wpo);
  gemm_bt<0><<<dim3(64, 24), 256, 0, stream>>>(xo, wqo, qkv, nullptr, nullptr);
  mhsa_attn<<<1024, 256, 0, stream>>>(qkv, aout);
  gemm_bt<1><<<dim3(64, 8), 256, 0, stream>>>(aout, wpo, nullptr, y, bp);
}